// Round 1
// baseline (720.996 us; speedup 1.0000x reference)
//
#include <hip/hip_runtime.h>
#include <stdint.h>
#include <stddef.h>

// ---------------------------------------------------------------------------
// StarBlock: out = relu( qlin(h, wd, bd) )
//   h    = floorq( pairsum( floorq(relu(qlin(x,w1,b1))) * floorq(qlin(x,w2,b2)) ) )
//   qlin(x,w,b) = x @ roundq(w,128).T + roundq(b,16384)
// B=32768, DIN=1024, DHID=2048, DOUT=1024
//
// Strategy:
//  * w1,w2 -> bf16 (q/128 is EXACT in bf16);  wd -> int8 (q).
//  * x split on-the-fly into hi/lo bf16 (trunc); 2 MFMA passes -> ~2^-15 rel err.
//  * up kernel: fused dual GEMM (w1,w2 share the x tile), epilogue does
//    relu/floor-quant/pair-sum/floor-quant exactly (all power-of-2 math),
//    stores h as int8.
//  * down kernel: i8 MFMA 16x16x64 (integer-exact), epilogue scale+bias+relu.
//  * LDS: global_load_lds(16B) with linear dest + involution swizzle applied to
//    the per-lane GLOBAL source and to the ds_read offset (guide rule #21).
//    Invariant: LDS[row][slot p] holds global slot q = p ^ (row & SMASK).
// ---------------------------------------------------------------------------

#define BROWS 32768
#define KDIN  1024
#define NHID  2048
#define NOUT  1024
#define HCOLS 1024

typedef __attribute__((ext_vector_type(4))) float    f32x4;
typedef __attribute__((ext_vector_type(4))) int      i32x4;
typedef __attribute__((ext_vector_type(8))) __bf16   bf16x8;
typedef __attribute__((ext_vector_type(8))) uint16_t u16x8;

typedef const __attribute__((address_space(1))) void* gas_ptr;
typedef __attribute__((address_space(3))) void*       las_ptr;

__device__ __forceinline__ void gload16(const void* g, void* l) {
  // dest is wave-uniform base; HW writes lane*16B
  __builtin_amdgcn_global_load_lds((gas_ptr)(uintptr_t)g,
                                   (las_ptr)(uint32_t)(uintptr_t)l, 16, 0, 0);
}

__device__ __forceinline__ uint16_t f32_bf16_rn(float f) {
  uint32_t u = __float_as_uint(f);
  return (uint16_t)((u + 0x7FFFu + ((u >> 16) & 1u)) >> 16);
}

// ---------------------------- prep kernels ---------------------------------

__global__ void quant_w_bf16_kernel(const float* __restrict__ in,
                                    uint16_t* __restrict__ out, int n4) {
  int stride = gridDim.x * blockDim.x;
  for (int i = blockIdx.x * blockDim.x + threadIdx.x; i < n4; i += stride) {
    float4 v = reinterpret_cast<const float4*>(in)[i];
    ushort4 o;
    o.x = f32_bf16_rn(rintf(fminf(fmaxf(v.x * 128.f, -128.f), 127.f)) * 0.0078125f);
    o.y = f32_bf16_rn(rintf(fminf(fmaxf(v.y * 128.f, -128.f), 127.f)) * 0.0078125f);
    o.z = f32_bf16_rn(rintf(fminf(fmaxf(v.z * 128.f, -128.f), 127.f)) * 0.0078125f);
    o.w = f32_bf16_rn(rintf(fminf(fmaxf(v.w * 128.f, -128.f), 127.f)) * 0.0078125f);
    reinterpret_cast<ushort4*>(out)[i] = o;
  }
}

__global__ void quant_w_i8_kernel(const float* __restrict__ in,
                                  int8_t* __restrict__ out, int n4) {
  int stride = gridDim.x * blockDim.x;
  for (int i = blockIdx.x * blockDim.x + threadIdx.x; i < n4; i += stride) {
    float4 v = reinterpret_cast<const float4*>(in)[i];
    char4 o;
    o.x = (int8_t)(int)rintf(fminf(fmaxf(v.x * 128.f, -128.f), 127.f));
    o.y = (int8_t)(int)rintf(fminf(fmaxf(v.y * 128.f, -128.f), 127.f));
    o.z = (int8_t)(int)rintf(fminf(fmaxf(v.z * 128.f, -128.f), 127.f));
    o.w = (int8_t)(int)rintf(fminf(fmaxf(v.w * 128.f, -128.f), 127.f));
    reinterpret_cast<char4*>(out)[i] = o;
  }
}

__global__ void quant_b_kernel(const float* __restrict__ in,
                               float* __restrict__ out, int n) {
  int i = blockIdx.x * blockDim.x + threadIdx.x;
  if (i < n) out[i] = rintf(in[i] * 16384.f) * (1.f / 16384.f);
}

// ------------------------- staging helpers ---------------------------------
// all tiles: 128 rows x 64 cols (elements), row-major, global ld = 1024 elems.

// f32 tile: row = 256B = 16 slots; swizzle mask 15. 32 chunks of 1024B.
__device__ __forceinline__ void stage_f32_tile(const float* g, float* lds,
                                               int lane, int c0) {
  int rl = lane >> 4;   // 0..3 rows per chunk
  int s  = lane & 15;   // physical 16B slot
#pragma unroll
  for (int i = 0; i < 16; ++i) {
    int c = c0 + i;
    int r = (c << 2) + rl;
    int gs = s ^ (r & 15);                    // source slot for this phys slot
    gload16(g + (size_t)r * KDIN + (gs << 2), lds + (c << 8));
  }
}

// bf16 tile: row = 128B = 8 slots; swizzle mask 7. 16 chunks of 1024B.
template <int CNT>
__device__ __forceinline__ void stage_bf16_tile(const uint16_t* g, uint16_t* lds,
                                                int lane, int c0) {
  int rl = lane >> 3;   // 0..7
  int s  = lane & 7;
#pragma unroll
  for (int i = 0; i < CNT; ++i) {
    int c = c0 + i;
    int r = (c << 3) + rl;
    int gs = s ^ rl;                          // r&7 == rl
    gload16(g + (size_t)r * KDIN + (gs << 3), lds + (c << 9));
  }
}

// i8 tile: row = 64B = 4 slots; swizzle mask 3. 8 chunks of 1024B.
template <int CNT>
__device__ __forceinline__ void stage_i8_tile(const int8_t* g, int8_t* lds,
                                              int lane, int c0) {
  int rl = lane >> 2;   // 0..15
  int s  = lane & 3;
#pragma unroll
  for (int i = 0; i < CNT; ++i) {
    int c = c0 + i;
    int r = (c << 4) + rl;
    int gs = s ^ (rl & 3);                    // r&3 == rl&3
    gload16(g + (size_t)r * (size_t)KDIN + (gs << 4), lds + (c << 10));
  }
}

// ------------------------- fragment readers --------------------------------

__device__ __forceinline__ bf16x8 frag_b16(const uint16_t* lds, int tr, int g) {
  int off = (tr << 6) + ((g ^ (tr & 7)) << 3);
  return __builtin_bit_cast(bf16x8, *reinterpret_cast<const u16x8*>(lds + off));
}

__device__ __forceinline__ i32x4 frag_i8(const int8_t* lds, int tr, int g) {
  int off = (tr << 6) + ((g ^ (tr & 3)) << 4);
  return *reinterpret_cast<const i32x4*>(lds + off);
}

// read 8 f32 (k = g*8..g*8+7) and emit truncated hi/lo bf16 fragments
__device__ __forceinline__ void frag_f32_hilo(const float* lds, int tr, int g,
                                              bf16x8& hi, bf16x8& lo) {
  int base = tr << 6;
  int q0 = ((g << 1)) ^ (tr & 15);
  int q1 = ((g << 1) | 1) ^ (tr & 15);
  f32x4 u0 = *reinterpret_cast<const f32x4*>(lds + base + (q0 << 2));
  f32x4 u1 = *reinterpret_cast<const f32x4*>(lds + base + (q1 << 2));
  u16x8 hu, lu;
#pragma unroll
  for (int i = 0; i < 4; ++i) {
    uint32_t b0 = __float_as_uint(u0[i]);
    uint32_t b1 = __float_as_uint(u1[i]);
    hu[i]     = (uint16_t)(b0 >> 16);
    hu[i + 4] = (uint16_t)(b1 >> 16);
    float r0 = u0[i] - __uint_as_float(b0 & 0xFFFF0000u);
    float r1 = u1[i] - __uint_as_float(b1 & 0xFFFF0000u);
    lu[i]     = (uint16_t)(__float_as_uint(r0) >> 16);
    lu[i + 4] = (uint16_t)(__float_as_uint(r1) >> 16);
  }
  hi = __builtin_bit_cast(bf16x8, hu);
  lo = __builtin_bit_cast(bf16x8, lu);
}

// ------------------------------ up kernel ----------------------------------
// grid 4096 = 256 row-tiles x 16 col-tiles (col fast for x-row L2 reuse)

__global__ __launch_bounds__(256, 2)
void up_kernel(const float* __restrict__ x,
               const uint16_t* __restrict__ w1q, const uint16_t* __restrict__ w2q,
               const float* __restrict__ b1q, const float* __restrict__ b2q,
               int8_t* __restrict__ hbuf) {
  __shared__ alignas(16) float    sA[128 * 64];   // 32 KB (f32 x tile)
  __shared__ alignas(16) uint16_t sB1[128 * 64];  // 16 KB
  __shared__ alignas(16) uint16_t sB2[128 * 64];  // 16 KB

  const int tid  = threadIdx.x;
  const int lane = tid & 63;
  const int wid  = tid >> 6;
  const int bm   = blockIdx.x >> 4;
  const int bn   = blockIdx.x & 15;
  const size_t row0 = (size_t)bm * 128;
  const int    col0 = bn * 128;

  const float*    xbase  = x   + row0 * KDIN;
  const uint16_t* w1base = w1q + (size_t)col0 * KDIN;
  const uint16_t* w2base = w2q + (size_t)col0 * KDIN;

  const f32x4 z4 = {0.f, 0.f, 0.f, 0.f};
  f32x4 acc1[4][4], acc2[4][4];
#pragma unroll
  for (int m = 0; m < 4; ++m)
#pragma unroll
    for (int n = 0; n < 4; ++n) { acc1[m][n] = z4; acc2[m][n] = z4; }

  const int wr = wid >> 1, wc = wid & 1;
  const int lrow = lane & 15, kg = lane >> 4;

  for (int t = 0; t < KDIN / 64; ++t) {
    __syncthreads();
    if (wid < 2)       stage_f32_tile(xbase + t * 64, sA, lane, wid << 4);
    else if (wid == 2) stage_bf16_tile<16>(w1base + t * 64, sB1, lane, 0);
    else               stage_bf16_tile<16>(w2base + t * 64, sB2, lane, 0);
    __syncthreads();

#pragma unroll
    for (int ks = 0; ks < 2; ++ks) {
      const int g = (ks << 2) + kg;
      bf16x8 bw1[4], bw2[4];
#pragma unroll
      for (int n = 0; n < 4; ++n) {
        const int tc = (wc << 6) + (n << 4) + lrow;
        bw1[n] = frag_b16(sB1, tc, g);
        bw2[n] = frag_b16(sB2, tc, g);
      }
#pragma unroll
      for (int m = 0; m < 4; ++m) {
        bf16x8 ah, al;
        frag_f32_hilo(sA, (wr << 6) + (m << 4) + lrow, g, ah, al);
#pragma unroll
        for (int n = 0; n < 4; ++n) {
          acc1[m][n] = __builtin_amdgcn_mfma_f32_16x16x32_bf16(ah, bw1[n], acc1[m][n], 0, 0, 0);
          acc1[m][n] = __builtin_amdgcn_mfma_f32_16x16x32_bf16(al, bw1[n], acc1[m][n], 0, 0, 0);
          acc2[m][n] = __builtin_amdgcn_mfma_f32_16x16x32_bf16(ah, bw2[n], acc2[m][n], 0, 0, 0);
          acc2[m][n] = __builtin_amdgcn_mfma_f32_16x16x32_bf16(al, bw2[n], acc2[m][n], 0, 0, 0);
        }
      }
    }
  }

  // epilogue: bias, relu, floor-quant, pairwise product-sum, floor-quant -> i8
#pragma unroll
  for (int n = 0; n < 4; ++n) {
    const int gc = col0 + (wc << 6) + (n << 4) + lrow;   // C col = lane&15
    const float bb1 = b1q[gc];
    const float bb2 = b2q[gc];
#pragma unroll
    for (int m = 0; m < 4; ++m) {
      const size_t gr0 = row0 + (wr << 6) + (m << 4) + (kg << 2);
#pragma unroll
      for (int j = 0; j < 4; ++j) {           // C row = (lane>>4)*4 + j
        float v1 = fmaxf(acc1[m][n][j] + bb1, 0.f);
        float q1 = floorf(fminf(v1 * 128.f, 127.f));             // in [0,127]
        float v2 = acc2[m][n][j] + bb2;
        float q2 = floorf(fminf(fmaxf(v2 * 128.f, -128.f), 127.f));
        float p  = q1 * q2;                                       // exact int
        float ps = p + __shfl_xor(p, 1, 64);                      // pair cols
        if (!(lane & 1)) {
          // h*128 = ps/128 exactly; floor+clip
          float hs = floorf(fminf(fmaxf(ps * 0.0078125f, -128.f), 127.f));
          hbuf[(gr0 + j) * HCOLS + (gc >> 1)] = (int8_t)(int)hs;
        }
      }
    }
  }
}

// ----------------------------- down kernel ---------------------------------
// out = relu( (h_i8 @ wd_i8.T) / 16384 + bdq ), i8 MFMA is integer-exact.
// grid 2048 = 256 row-tiles x 8 col-tiles

__global__ __launch_bounds__(256, 2)
void down_kernel(const int8_t* __restrict__ hbuf, const int8_t* __restrict__ wdq,
                 const float* __restrict__ bdq, float* __restrict__ out) {
  __shared__ alignas(16) int8_t sA[128 * 64];   // 8 KB
  __shared__ alignas(16) int8_t sB[128 * 64];   // 8 KB

  const int tid  = threadIdx.x;
  const int lane = tid & 63;
  const int wid  = tid >> 6;
  const int bm   = blockIdx.x >> 3;
  const int bn   = blockIdx.x & 7;
  const size_t row0 = (size_t)bm * 128;
  const int    col0 = bn * 128;

  const int8_t* hbase = hbuf + row0 * HCOLS;
  const int8_t* wbase = wdq + (size_t)col0 * HCOLS;

  const i32x4 z4 = {0, 0, 0, 0};
  i32x4 acc[4][4];
#pragma unroll
  for (int m = 0; m < 4; ++m)
#pragma unroll
    for (int n = 0; n < 4; ++n) acc[m][n] = z4;

  const int wr = wid >> 1, wc = wid & 1;
  const int lrow = lane & 15, kg = lane >> 4;   // kg selects 16B k-group (K=64)

  for (int t = 0; t < HCOLS / 64; ++t) {
    __syncthreads();
    if (wid < 2) stage_i8_tile<4>(hbase + t * 64, sA, lane, wid << 2);
    else         stage_i8_tile<4>(wbase + t * 64, sB, lane, (wid - 2) << 2);
    __syncthreads();

    i32x4 a[4], b[4];
#pragma unroll
    for (int m = 0; m < 4; ++m) a[m] = frag_i8(sA, (wr << 6) + (m << 4) + lrow, kg);
#pragma unroll
    for (int n = 0; n < 4; ++n) b[n] = frag_i8(sB, (wc << 6) + (n << 4) + lrow, kg);
#pragma unroll
    for (int m = 0; m < 4; ++m)
#pragma unroll
      for (int n = 0; n < 4; ++n)
        acc[m][n] = __builtin_amdgcn_mfma_i32_16x16x64_i8(a[m], b[n], acc[m][n], 0, 0, 0);
  }

#pragma unroll
  for (int n = 0; n < 4; ++n) {
    const int gc = col0 + (wc << 6) + (n << 4) + lrow;
    const float bb = bdq[gc];
#pragma unroll
    for (int m = 0; m < 4; ++m) {
      const size_t gr0 = row0 + (wr << 6) + (m << 4) + (kg << 2);
#pragma unroll
      for (int j = 0; j < 4; ++j)
        out[(gr0 + j) * NOUT + gc] =
            fmaxf((float)acc[m][n][j] * (1.f / 16384.f) + bb, 0.f);
    }
  }
}

// ------------------------------- launch ------------------------------------

extern "C" void kernel_launch(void* const* d_in, const int* in_sizes, int n_in,
                              void* d_out, int out_size, void* d_ws, size_t ws_size,
                              hipStream_t stream) {
  const float* x  = (const float*)d_in[0];
  const float* w1 = (const float*)d_in[1];
  const float* b1 = (const float*)d_in[2];
  const float* w2 = (const float*)d_in[3];
  const float* b2 = (const float*)d_in[4];
  const float* wd = (const float*)d_in[5];
  const float* bd = (const float*)d_in[6];
  float* out = (float*)d_out;

  // workspace layout (43 MB total)
  char* ws = (char*)d_ws;
  int8_t*   hbuf = (int8_t*)(ws);                        // 32 MB
  uint16_t* w1q  = (uint16_t*)(ws + 33554432);           // 4 MB
  uint16_t* w2q  = (uint16_t*)(ws + 37748736);           // 4 MB
  int8_t*   wdq  = (int8_t*)(ws + 41943040);             // 1 MB
  float*    b1q  = (float*)(ws + 42991616);              // 8 KB
  float*    b2q  = (float*)(ws + 42999808);              // 8 KB
  float*    bdq  = (float*)(ws + 43008000);              // 4 KB

  quant_w_bf16_kernel<<<512, 256, 0, stream>>>(w1, w1q, NHID * KDIN / 4);
  quant_w_bf16_kernel<<<512, 256, 0, stream>>>(w2, w2q, NHID * KDIN / 4);
  quant_w_i8_kernel<<<256, 256, 0, stream>>>(wd, wdq, NOUT * HCOLS / 4);
  quant_b_kernel<<<8, 256, 0, stream>>>(b1, b1q, NHID);
  quant_b_kernel<<<8, 256, 0, stream>>>(b2, b2q, NHID);
  quant_b_kernel<<<4, 256, 0, stream>>>(bd, bdq, NOUT);

  up_kernel<<<4096, 256, 0, stream>>>(x, w1q, w2q, b1q, b2q, hbuf);
  down_kernel<<<2048, 256, 0, stream>>>(hbuf, wdq, bdq, out);
}